// Round 2
// baseline (488.805 us; speedup 1.0000x reference)
//
#include <hip/hip_runtime.h>
#include <math.h>

#define NEG 0.2f

// ---------------------------------------------------------------------------
// CSR build: histogram -> single-block exclusive scan -> scatter
// ---------------------------------------------------------------------------
__global__ void k_hist(const int* __restrict__ dst, int E, int* __restrict__ deg) {
    int i = blockIdx.x * 256 + threadIdx.x;
    if (i < E) atomicAdd(&deg[dst[i]], 1);
}

__global__ __launch_bounds__(1024) void k_scan2(int* a, int na, int* b, int nb) {
    int* p = (blockIdx.x == 0) ? a : b;
    int n  = (blockIdx.x == 0) ? na : nb;
    __shared__ int sums[1024];
    int t = threadIdx.x;
    int C = (n + 1023) >> 10;
    int base = t * C;
    int s = 0;
    for (int j = 0; j < C; ++j) { int i = base + j; if (i < n) s += p[i]; }
    sums[t] = s;
    __syncthreads();
    for (int off = 1; off < 1024; off <<= 1) {
        int v = (t >= off) ? sums[t - off] : 0;
        __syncthreads();
        sums[t] += v;
        __syncthreads();
    }
    int run = (t == 0) ? 0 : sums[t - 1];
    for (int j = 0; j < C; ++j) {
        int i = base + j;
        if (i < n) { int v = p[i]; p[i] = run; run += v; }
    }
}

__global__ void k_scatter(const int* __restrict__ src, const int* __restrict__ dst,
                          int E, int* __restrict__ cur, int* __restrict__ csr) {
    int i = blockIdx.x * 256 + threadIdx.x;
    if (i < E) {
        int d = dst[i];
        int pos = atomicAdd(&cur[d], 1);
        csr[pos] = src[i];
    }
}

// ---------------------------------------------------------------------------
// helpers
// ---------------------------------------------------------------------------
static __device__ __forceinline__ void fma4(float4& d, float s, const float4 w) {
    d.x = fmaf(s, w.x, d.x); d.y = fmaf(s, w.y, d.y);
    d.z = fmaf(s, w.z, d.z); d.w = fmaf(s, w.w, d.w);
}
static __device__ __forceinline__ float4 lrelu4(float4 a, float4 b) {
    float4 r;
    float v;
    v = a.x + b.x; r.x = (v > 0.f) ? v : NEG * v;
    v = a.y + b.y; r.y = (v > 0.f) ? v : NEG * v;
    v = a.z + b.z; r.z = (v > 0.f) ? v : NEG * v;
    v = a.w + b.w; r.w = (v > 0.f) ? v : NEG * v;
    return r;
}

// ---------------------------------------------------------------------------
// GATv2 layer: TWO nodes per wave (half-wave each). Lane q=lane&31 owns 8
// contiguous dims d0=q*8 of the 256; lanes q 8h..8h+7 form head h, so the
// score reduce is 3 shfl_xor(width 8) per edge-PAIR. fs computed on the fly
// (8 indep FMA chains/lane -> issue-bound, latency hidden). Grid-stride
// persistent blocks amortize the 44KB weight staging + wave constants.
// ---------------------------------------------------------------------------
__global__ __launch_bounds__(256) void k_gat(
    const float* __restrict__ x_src, const float* __restrict__ x_dst,
    const int* __restrict__ pfx, const int* __restrict__ csr,
    const float* __restrict__ Ws, const float* __restrict__ bs,
    const float* __restrict__ Wd, const float* __restrict__ bd,
    const float* __restrict__ attn,
    const float* __restrict__ Wr, const float* __restrict__ br,
    float* __restrict__ xcat, int n_dst, int col_off)
{
    __shared__ __align__(16) float sWd[16 * 256];
    __shared__ __align__(16) float sWr[16 * 256];
    __shared__ __align__(16) float sWs[8 * 256];
    __shared__ __align__(16) float sB[4 * 256];   // bs | bd | br | attn

    int t = threadIdx.x;
#pragma unroll
    for (int i = 0; i < 4; ++i)
        ((float4*)sWd)[t + i * 256] = ((const float4*)Wd)[t + i * 256];
#pragma unroll
    for (int i = 0; i < 4; ++i)
        ((float4*)sWr)[t + i * 256] = ((const float4*)Wr)[t + i * 256];
#pragma unroll
    for (int i = 0; i < 2; ++i)
        ((float4*)sWs)[t + i * 256] = ((const float4*)Ws)[t + i * 256];
    if (t < 64)       ((float4*)(sB      ))[t      ] = ((const float4*)bs  )[t      ];
    else if (t < 128) ((float4*)(sB + 256))[t - 64 ] = ((const float4*)bd  )[t - 64 ];
    else if (t < 192) ((float4*)(sB + 512))[t - 128] = ((const float4*)br  )[t - 128];
    else              ((float4*)(sB + 768))[t - 192] = ((const float4*)attn)[t - 192];
    __syncthreads();

    int wave = t >> 6, lane = t & 63;
    int half = lane >> 5;          // which node of the pair
    int q    = lane & 31;          // dim group
    int d0   = q * 8;

    // wave-lifetime per-lane constants
    float4 wsL[8], wsH[8];
#pragma unroll
    for (int k = 0; k < 8; ++k) {
        wsL[k] = *(const float4*)&sWs[k * 256 + d0];
        wsH[k] = *(const float4*)&sWs[k * 256 + d0 + 4];
    }
    float4 bsL = *(const float4*)&sB[d0],       bsH = *(const float4*)&sB[d0 + 4];
    float4 atL = *(const float4*)&sB[768 + d0], atH = *(const float4*)&sB[768 + d0 + 4];

    int npairs = (n_dst + 1) >> 1;
    int gw = blockIdx.x * 4 + wave;
    int gstride = gridDim.x * 4;

    for (int pair = gw; pair < npairs; pair += gstride) {
        int node = pair * 2 + half;
        bool valid = node < n_dst;
        int nd = valid ? node : 0;
        int end   = pfx[nd];
        int start = nd ? pfx[nd - 1] : 0;
        int deg   = valid ? (end - start) : 0;

        // fd = x_dst@Wd + bd, fr = x_dst@Wr + br  (this node's 8 dims/lane)
        float4 fdL = *(const float4*)&sB[256 + d0];
        float4 fdH = *(const float4*)&sB[256 + d0 + 4];
        float4 frL = *(const float4*)&sB[512 + d0];
        float4 frH = *(const float4*)&sB[512 + d0 + 4];
        const float* xr = x_dst + (size_t)nd * 16;
#pragma unroll
        for (int kq = 0; kq < 4; ++kq) {
            float4 xv = *(const float4*)&xr[kq * 4];
#pragma unroll
            for (int kk = 0; kk < 4; ++kk) {
                int k = kq * 4 + kk;
                float xk = (kk == 0) ? xv.x : (kk == 1) ? xv.y : (kk == 2) ? xv.z : xv.w;
                fma4(fdL, xk, *(const float4*)&sWd[k * 256 + d0]);
                fma4(fdH, xk, *(const float4*)&sWd[k * 256 + d0 + 4]);
                fma4(frL, xk, *(const float4*)&sWr[k * 256 + d0]);
                fma4(frH, xk, *(const float4*)&sWr[k * 256 + d0 + 4]);
            }
        }

        float m = -INFINITY, l = 0.f;
        float4 accL = make_float4(0.f, 0.f, 0.f, 0.f);
        float4 accH = make_float4(0.f, 0.f, 0.f, 0.f);

        int dm = max(deg, __shfl_xor(deg, 32, 64));   // uniform trip count

        // 2-deep pipeline over this node's edges
        int s1 = (deg > 0) ? csr[start] : 0;
        int s2 = (deg > 1) ? csr[start + 1] : 0;
        float4 f0 = *(const float4*)&x_src[(size_t)s1 * 8];
        float4 f1 = *(const float4*)&x_src[(size_t)s1 * 8 + 4];
        for (int e = 0; e < dm; ++e) {
            float4 g0 = *(const float4*)&x_src[(size_t)s2 * 8];
            float4 g1 = *(const float4*)&x_src[(size_t)s2 * 8 + 4];
            int s3 = (e + 2 < deg) ? csr[start + e + 2] : 0;

            float4 fsL = bsL, fsH = bsH;
            fma4(fsL, f0.x, wsL[0]); fma4(fsH, f0.x, wsH[0]);
            fma4(fsL, f0.y, wsL[1]); fma4(fsH, f0.y, wsH[1]);
            fma4(fsL, f0.z, wsL[2]); fma4(fsH, f0.z, wsH[2]);
            fma4(fsL, f0.w, wsL[3]); fma4(fsH, f0.w, wsH[3]);
            fma4(fsL, f1.x, wsL[4]); fma4(fsH, f1.x, wsH[4]);
            fma4(fsL, f1.y, wsL[5]); fma4(fsH, f1.y, wsH[5]);
            fma4(fsL, f1.z, wsL[6]); fma4(fsH, f1.z, wsH[6]);
            fma4(fsL, f1.w, wsL[7]); fma4(fsH, f1.w, wsH[7]);

            float4 tL = lrelu4(fsL, fdL);
            float4 tH = lrelu4(fsH, fdH);
            float sc = tL.x * atL.x;
            sc = fmaf(tL.y, atL.y, sc);
            sc = fmaf(tL.z, atL.z, sc);
            sc = fmaf(tL.w, atL.w, sc);
            sc = fmaf(tH.x, atH.x, sc);
            sc = fmaf(tH.y, atH.y, sc);
            sc = fmaf(tH.z, atH.z, sc);
            sc = fmaf(tH.w, atH.w, sc);
            // reduce across the 8 lanes of this head (uniform participation)
            sc += __shfl_xor(sc, 1, 8);
            sc += __shfl_xor(sc, 2, 8);
            sc += __shfl_xor(sc, 4, 8);

            if (e < deg) {   // all 32 lanes of a half share this predicate
                float mn = fmaxf(m, sc);
                float corr = __expf(m - mn);    // 0 on first edge (m = -inf)
                float p = __expf(sc - mn);
                l = fmaf(l, corr, p);
                accL.x = fmaf(accL.x, corr, p * fsL.x);
                accL.y = fmaf(accL.y, corr, p * fsL.y);
                accL.z = fmaf(accL.z, corr, p * fsL.z);
                accL.w = fmaf(accL.w, corr, p * fsL.w);
                accH.x = fmaf(accH.x, corr, p * fsH.x);
                accH.y = fmaf(accH.y, corr, p * fsH.y);
                accH.z = fmaf(accH.z, corr, p * fsH.z);
                accH.w = fmaf(accH.w, corr, p * fsH.w);
                m = mn;
            }
            f0 = g0; f1 = g1; s2 = s3;
        }

        if (valid) {
            float inv = (l > 0.f) ? 1.f / l : 0.f;   // zero in-degree -> rst = 0
            float4 oL, oH;
            oL.x = fmaxf(fmaf(accL.x, inv, frL.x), 0.f);
            oL.y = fmaxf(fmaf(accL.y, inv, frL.y), 0.f);
            oL.z = fmaxf(fmaf(accL.z, inv, frL.z), 0.f);
            oL.w = fmaxf(fmaf(accL.w, inv, frL.w), 0.f);
            oH.x = fmaxf(fmaf(accH.x, inv, frH.x), 0.f);
            oH.y = fmaxf(fmaf(accH.y, inv, frH.y), 0.f);
            oH.z = fmaxf(fmaf(accH.z, inv, frH.z), 0.f);
            oH.w = fmaxf(fmaf(accH.w, inv, frH.w), 0.f);
            float* op = &xcat[(size_t)node * 512 + col_off + d0];
            *(float4*)op = oL;
            *(float4*)(op + 4) = oH;
        }
    }
}

// ---------------------------------------------------------------------------
// out = relu(X[M,512] @ W[512,256] + b). f32 vector GEMM, KT=32 LDS tiles.
// Block: 256 threads, 16 rows x 256 cols; thread = 4 rows x 4 cols.
// ---------------------------------------------------------------------------
#define KT 32
__global__ __launch_bounds__(256) void k_mlp(
    const float* __restrict__ X, const float* __restrict__ W,
    const float* __restrict__ b, float* __restrict__ out, int M)
{
    __shared__ __align__(16) float sW[KT * 256];   // 32 KB
    __shared__ __align__(16) float sX[16 * KT];    // 2 KB
    int t = threadIdx.x;
    int rbase = blockIdx.x * 16;
    int col_q = t & 63;   // cols col_q*4 .. +3
    int row_q = t >> 6;   // rows row_q*4 .. +3 (within 16-row tile)
    float acc[4][4] = {};

    for (int k0 = 0; k0 < 512; k0 += KT) {
        __syncthreads();
#pragma unroll
        for (int i = 0; i < 8; ++i) {
            int idx = t + i * 256;
            ((float4*)sW)[idx] = ((const float4*)(W + k0 * 256))[idx];
        }
        if (t < 128) {
            int r = t >> 3;
            int qq = t & 7;
            int row = rbase + r;
            float4 v = (row < M) ? *(const float4*)&X[(size_t)row * 512 + k0 + qq * 4]
                                 : make_float4(0.f, 0.f, 0.f, 0.f);
            *(float4*)&sX[r * KT + qq * 4] = v;
        }
        __syncthreads();
#pragma unroll 4
        for (int k = 0; k < KT; ++k) {
            float4 w = *(const float4*)&sW[k * 256 + col_q * 4];
#pragma unroll
            for (int r = 0; r < 4; ++r) {
                float x = sX[(row_q * 4 + r) * KT + k];
                acc[r][0] = fmaf(x, w.x, acc[r][0]);
                acc[r][1] = fmaf(x, w.y, acc[r][1]);
                acc[r][2] = fmaf(x, w.z, acc[r][2]);
                acc[r][3] = fmaf(x, w.w, acc[r][3]);
            }
        }
    }
    float4 bias = *(const float4*)&b[col_q * 4];
#pragma unroll
    for (int r = 0; r < 4; ++r) {
        int row = rbase + row_q * 4 + r;
        if (row < M) {
            float4 o;
            o.x = fmaxf(acc[r][0] + bias.x, 0.f);
            o.y = fmaxf(acc[r][1] + bias.y, 0.f);
            o.z = fmaxf(acc[r][2] + bias.z, 0.f);
            o.w = fmaxf(acc[r][3] + bias.w, 0.f);
            *(float4*)&out[(size_t)row * 256 + col_q * 4] = o;
        }
    }
}

// ---------------------------------------------------------------------------
extern "C" void kernel_launch(void* const* d_in, const int* in_sizes, int n_in,
                              void* d_out, int out_size, void* d_ws, size_t ws_size,
                              hipStream_t stream) {
    const float* x_gt   = (const float*)d_in[0];
    const float* x_ubs  = (const float*)d_in[1];
    const float* x_ag   = (const float*)d_in[2];
    const int* seen_src = (const int*)d_in[3];
    const int* seen_dst = (const int*)d_in[4];
    const int* near_src = (const int*)d_in[5];
    const int* near_dst = (const int*)d_in[6];
    const float* Ws_s = (const float*)d_in[7];  const float* bs_s = (const float*)d_in[8];
    const float* Wd_s = (const float*)d_in[9];  const float* bd_s = (const float*)d_in[10];
    const float* at_s = (const float*)d_in[11];
    const float* Wr_s = (const float*)d_in[12]; const float* br_s = (const float*)d_in[13];
    const float* Ws_n = (const float*)d_in[14]; const float* bs_n = (const float*)d_in[15];
    const float* Wd_n = (const float*)d_in[16]; const float* bd_n = (const float*)d_in[17];
    const float* at_n = (const float*)d_in[18];
    const float* Wr_n = (const float*)d_in[19]; const float* br_n = (const float*)d_in[20];
    const float* W_a  = (const float*)d_in[21]; const float* b_a  = (const float*)d_in[22];

    const int n_ag = in_sizes[2] / 16;
    const int E_s  = in_sizes[3];
    const int E_n  = in_sizes[5];

    char* ws = (char*)d_ws;
    int* cur_s = (int*)ws;  ws += (size_t)n_ag * 4;
    int* cur_n = (int*)ws;  ws += (size_t)n_ag * 4;
    int* csr_s = (int*)ws;  ws += (size_t)E_s * 4;
    int* csr_n = (int*)ws;  ws += (size_t)E_n * 4;
    float* xcat = (float*)ws;   // [n_ag, 512]

    hipMemsetAsync(cur_s, 0, (size_t)n_ag * 8, stream);  // cur_s, cur_n contiguous

    k_hist<<<(E_s + 255) / 256, 256, 0, stream>>>(seen_dst, E_s, cur_s);
    k_hist<<<(E_n + 255) / 256, 256, 0, stream>>>(near_dst, E_n, cur_n);
    k_scan2<<<2, 1024, 0, stream>>>(cur_s, n_ag, cur_n, n_ag);
    k_scatter<<<(E_s + 255) / 256, 256, 0, stream>>>(seen_src, seen_dst, E_s, cur_s, csr_s);
    k_scatter<<<(E_n + 255) / 256, 256, 0, stream>>>(near_src, near_dst, E_n, cur_n, csr_n);

    // persistent grid: 3 blocks/CU (44KB LDS each), grid-stride over node pairs
    k_gat<<<768, 256, 0, stream>>>(x_gt, x_ag, cur_s, csr_s,
        Ws_s, bs_s, Wd_s, bd_s, at_s, Wr_s, br_s, xcat, n_ag, 0);
    k_gat<<<768, 256, 0, stream>>>(x_ubs, x_ag, cur_n, csr_n,
        Ws_n, bs_n, Wd_n, bd_n, at_n, Wr_n, br_n, xcat, n_ag, 256);

    k_mlp<<<(n_ag + 15) / 16, 256, 0, stream>>>(xcat, W_a, b_a, (float*)d_out, n_ag);
}